// Round 1
// 161.618 us; speedup vs baseline: 1.0478x; 1.0478x over previous
//
#include <hip/hip_runtime.h>
#include <hip/hip_bf16.h>

typedef __bf16 bf16;
typedef __attribute__((ext_vector_type(8))) __bf16 bf16x8;
typedef __attribute__((ext_vector_type(4))) __bf16 bf16x4;
typedef __attribute__((ext_vector_type(16))) float f32x16;

#define N_ROWS 16384
#define DIM 256
#define NJC 512           /* 32-col tiles */
#define LSTRIP 16         /* col-tiles per block */
#define NSTRIPS 2112      /* sum_{it} ceil((512-4it)/16) == 2112 */
#define SQK1 4.53981608f  /* sqrt(1/(0.07*ln2)): A pre-scaled so e^{z} = 2^{dot'} */
#define LN2F 0.69314718056f

#define WS_T_OFF (N_ROWS * DIM * 2)
#define WS_D_OFF (WS_T_OFF + N_ROWS * 4)

#define GLOAD_LDS(g, l)                                        \
    __builtin_amdgcn_global_load_lds(                          \
        (const __attribute__((address_space(1))) void*)(g),    \
        (__attribute__((address_space(3))) void*)(l), 16, 0, 0)

// Kernel 1: L2-normalize rows, scale by SQK1, emit bf16 A' to ws. Zeros T[]
// and d_out. Dg[row] = s2' = sum(bf16(SQK1*a)^2) = the MFMA diagonal, so the
// diagonal's bf16 rounding error cancels: loss_i = ln2*(log2(T'_i) - s2'_i).
__global__ void __launch_bounds__(256) normalize_kernel(const float* __restrict__ in,
                                                        bf16* __restrict__ out,
                                                        float* __restrict__ Tg,
                                                        float* __restrict__ Dg,
                                                        float* __restrict__ loss_out) {
    if (blockIdx.x == 0 && threadIdx.x == 0) loss_out[0] = 0.0f;
    if (blockIdx.x < 64) Tg[blockIdx.x * 256 + threadIdx.x] = 0.0f;

    const int row  = blockIdx.x * 4 + (threadIdx.x >> 6);
    const int lane = threadIdx.x & 63;
    const float4* rp = (const float4*)(in + (size_t)row * DIM);
    float4 v = rp[lane];
    float ss = v.x * v.x + v.y * v.y + v.z * v.z + v.w * v.w;
#pragma unroll
    for (int m = 1; m < 64; m <<= 1) ss += __shfl_xor(ss, m, 64);
    float inv = SQK1 / fmaxf(sqrtf(ss), 1e-12f);
    bf16x4 o;
    o[0] = (bf16)(v.x * inv);
    o[1] = (bf16)(v.y * inv);
    o[2] = (bf16)(v.z * inv);
    o[3] = (bf16)(v.w * inv);
    *(bf16x4*)(out + (size_t)row * DIM + lane * 4) = o;

    float f0 = (float)o[0], f1 = (float)o[1], f2 = (float)o[2], f3 = (float)o[3];
    float s2 = f0 * f0 + f1 * f1 + f2 * f2 + f3 * f3;
#pragma unroll
    for (int m = 1; m < 64; m <<= 1) s2 += __shfl_xor(s2, m, 64);
    if (lane == 0) Dg[row] = s2;
}

// Tree-reduce 16 floats across the 32 `lo` lanes; every lane ends with the
// full sum for register index r = (lo>>1)&15. (Correctness-proven R4-R10.)
#define TREE16(R, out)                                                     \
    do {                                                                   \
        float w8[8], w4[4], w2[2], w1, g_;                                 \
        _Pragma("unroll") for (int i_ = 0; i_ < 8; ++i_) {                 \
            g_ = (lo & 16) ? R[i_] : R[i_ + 8];                            \
            w8[i_] = ((lo & 16) ? R[i_ + 8] : R[i_]) + __shfl_xor(g_, 16); \
        }                                                                  \
        _Pragma("unroll") for (int i_ = 0; i_ < 4; ++i_) {                 \
            g_ = (lo & 8) ? w8[i_] : w8[i_ + 4];                           \
            w4[i_] = ((lo & 8) ? w8[i_ + 4] : w8[i_]) + __shfl_xor(g_, 8); \
        }                                                                  \
        _Pragma("unroll") for (int i_ = 0; i_ < 2; ++i_) {                 \
            g_ = (lo & 4) ? w4[i_] : w4[i_ + 2];                           \
            w2[i_] = ((lo & 4) ? w4[i_ + 2] : w4[i_]) + __shfl_xor(g_, 4); \
        }                                                                  \
        g_ = (lo & 2) ? w2[0] : w2[1];                                     \
        w1 = ((lo & 2) ? w2[1] : w2[0]) + __shfl_xor(g_, 2);               \
        out = w1 + __shfl_xor(w1, 1);                                      \
    } while (0)

// Kernel 2: symmetric A'A'^T + softmax denominator.
// R11 -> R12 change: 128x32 tiles, 4-wave blocks (one 32-row group per wave,
// each wave spans the full 32-col tile). Per-wave work per tile is identical
// to R11 (16 ds_read_b128 + 16 chained MFMA + 16 exp2), but the CU now hosts
// FOUR independent barrier groups (4 blocks x 16 KB dbuf LDS = 128 KB)
// instead of two. Theory: R11's ~50% per-tile bubble was block-lockstep
// phase alignment (LDS-heavy k-loop vs VALU/trans epilogue vs DMA wait);
// 4 anti-phased blocks fill the complementary pipes. CsAcc is gone: column
// sums flush with one predicated atomicAdd per wave per tile (fire-and-
// forget; the atomic is OLDER than the next tile's 4 staging loads, so
// s_waitcnt vmcnt(4) still guarantees the current tile's staging retired).
__global__ void __launch_bounds__(256, 4)
loss_kernel(const bf16* __restrict__ A, float* __restrict__ Tg) {
    __shared__ bf16 Bs0[32 * DIM];          // 16 KB
    __shared__ bf16 Bs1[32 * DIM];          // 16 KB

    const int tid = threadIdx.x;
    const int w  = tid >> 6;      // wave = row-group: rows w*32..+31 of the 128-row strip
    const int l  = tid & 63;
    const int lo = l & 31, hi = l >> 5;

    // strip decode: (it, chunk of up to 16 col-tiles starting at jc0 >= 4*it)
    int it = 0, rem = blockIdx.x;
    for (;;) {
        const int nch = 32 - (it >> 2);   // ceil((512-4it)/16)
        if (rem < nch) break;
        rem -= nch;
        ++it;
    }
    const int jc0 = 4 * it + rem * LSTRIP;
    const int jc1 = (jc0 + LSTRIP < NJC) ? (jc0 + LSTRIP) : NJC;

    // persistent A fragments for the wave's 32 rows (A-op: m=lo, k=hi*8+j)
    bf16x8 af[16];
    {
        const bf16* ap = A + (size_t)(it * 128 + w * 32 + lo) * DIM + hi * 8;
#pragma unroll
        for (int k = 0; k < 16; ++k)
            af[k] = *(const volatile bf16x8*)(ap + k * 16);
    }

    float s0[16];
#pragma unroll
    for (int r = 0; r < 16; ++r) s0[r] = 0.f;

    // DMA lane constants. Wave w stages B-tile rows w*8..+7 in 4 instrs
    // (2 rows each). Lane: rl = l>>5 (row in pair), s = l&31 (LDS slot).
    // Slot s of row r holds global chunk c = (s&24)|((s&7)^(r&7)).
    const int s_dma = l & 31;
    const int rl    = l >> 5;
    int vo[4];
#pragma unroll
    for (int q = 0; q < 4; ++q) {
        const int c = (s_dma & 24) | ((s_dma & 7) ^ ((q * 2 + rl) & 7));
        vo[q] = rl * DIM + c * 8;
    }

    // fragment-read constants: B row = lo; chunk cc at slot (cc&24)|((cc&7)^(lo&7))
    const int rbase = lo * DIM;
    const int mx7 = lo & 7;

#define ISSUE(jcn, BUF)                                                      \
    do {                                                                     \
        const bf16* tb_ = A + (size_t)((jcn) * 32 + w * 8) * DIM;            \
        bf16* lb_ = &BUF[(w * 8) * DIM];                                     \
        _Pragma("unroll") for (int q_ = 0; q_ < 4; ++q_) {                   \
            GLOAD_LDS(tb_ + (q_ * 2) * DIM + vo[q_],                         \
                      lb_ + (q_ * 2) * DIM);                                 \
        }                                                                    \
    } while (0)

#define TILE_BODY(BR, BW, jc)                                                \
    do {                                                                     \
        asm volatile("s_barrier" ::: "memory");                              \
        if ((jc) + 1 < jc1) {                                                \
            ISSUE((jc) + 1, BW);                                             \
            asm volatile("s_waitcnt vmcnt(4)" ::: "memory");                 \
        } else {                                                             \
            asm volatile("s_waitcnt vmcnt(0)" ::: "memory");                 \
        }                                                                    \
        asm volatile("s_barrier" ::: "memory");                              \
        f32x16 c0;                                                           \
        _Pragma("unroll") for (int r_ = 0; r_ < 16; ++r_) c0[r_] = 0.f;      \
        __builtin_amdgcn_s_setprio(1);                                       \
        _Pragma("unroll") for (int k_ = 0; k_ < 16; ++k_) {                  \
            const int cc_ = k_ * 2 + hi;                                     \
            const int slot_ = (cc_ & 24) | ((cc_ & 7) ^ mx7);                \
            bf16x8 b_ = *(const bf16x8*)&BR[rbase + slot_ * 8];              \
            c0 = __builtin_amdgcn_mfma_f32_32x32x16_bf16(af[k_], b_, c0, 0, 0, 0); \
        }                                                                    \
        __builtin_amdgcn_s_setprio(0);                                       \
        float cs_ = 0.f;                                                     \
        _Pragma("unroll") for (int r_ = 0; r_ < 16; ++r_) {                  \
            float e_ = __builtin_amdgcn_exp2f(c0[r_]);                       \
            s0[r_] += e_;                                                    \
            cs_ += e_;                                                       \
        }                                                                    \
        cs_ += __shfl_xor(cs_, 32);                                          \
        /* col-sum flush; skip the diagonal 128x128 block (jc>>2 == it):    \
           its entries are fully covered by row sums. */                     \
        if (((jc) >> 2) != it && hi == 0)                                    \
            atomicAdd(&Tg[(jc) * 32 + lo], cs_);                             \
    } while (0)

    ISSUE(jc0, Bs0);
    int jc = jc0;
    while (jc < jc1) {
        TILE_BODY(Bs0, Bs1, jc);
        ++jc;
        if (jc >= jc1) break;
        TILE_BODY(Bs1, Bs0, jc);
        ++jc;
    }

    // strip end: row sums. C/D row = (r&3)+8*(r>>2)+4*hi; even `lo` lanes
    // hold the tree result for r=(lo>>1).
    float t0;
    TREE16(s0, t0);
    const int r = (lo >> 1) & 15;
    const int rowoff = (r & 3) + 8 * (r >> 2) + 4 * hi;
    if ((l & 1) == 0)
        atomicAdd(&Tg[it * 128 + w * 32 + rowoff], t0);
#undef ISSUE
#undef TILE_BODY
}

// Kernel 3: loss_i = ln2*(log2(T'_i) - s2'_i), mean over rows.
__global__ void __launch_bounds__(256) final_kernel(const float* __restrict__ Tg,
                                                    const float* __restrict__ Dg,
                                                    float* __restrict__ out) {
    __shared__ float red[4];
    const int i = blockIdx.x * 256 + threadIdx.x;
    float c = LN2F * (__log2f(Tg[i]) - Dg[i]) * (1.0f / (float)N_ROWS);
#pragma unroll
    for (int m = 1; m < 64; m <<= 1) c += __shfl_xor(c, m, 64);
    if ((threadIdx.x & 63) == 0) red[threadIdx.x >> 6] = c;
    __syncthreads();
    if (threadIdx.x == 0)
        atomicAdd(out, red[0] + red[1] + red[2] + red[3]);
}

extern "C" void kernel_launch(void* const* d_in, const int* in_sizes, int n_in,
                              void* d_out, int out_size, void* d_ws, size_t ws_size,
                              hipStream_t stream) {
    const float* emb = (const float*)d_in[0];
    float* out = (float*)d_out;
    bf16* Abf = (bf16*)d_ws;
    float* Tg = (float*)((char*)d_ws + WS_T_OFF);
    float* Dg = (float*)((char*)d_ws + WS_D_OFF);

    hipLaunchKernelGGL(normalize_kernel, dim3(N_ROWS / 4), dim3(256), 0, stream,
                       emb, Abf, Tg, Dg, out);
    hipLaunchKernelGGL(loss_kernel, dim3(NSTRIPS), dim3(256), 0, stream,
                       Abf, Tg);
    hipLaunchKernelGGL(final_kernel, dim3(N_ROWS / 256), dim3(256), 0, stream,
                       Tg, Dg, out);
}

// Round 3
// 156.335 us; speedup vs baseline: 1.0832x; 1.0338x over previous
//
#include <hip/hip_runtime.h>
#include <hip/hip_bf16.h>

typedef __bf16 bf16;
typedef __attribute__((ext_vector_type(8))) __bf16 bf16x8;
typedef __attribute__((ext_vector_type(4))) __bf16 bf16x4;
typedef __attribute__((ext_vector_type(16))) float f32x16;

#define N_ROWS 16384
#define DIM 256
#define NJC 512           /* 32-col tiles */
#define NBLKS 1024        /* exactly one resident round: 4 blocks/CU x 256 CU */
#define NTILES 33024      /* sum_{it=0}^{127} (512-4it) */
#define SQK1 4.53981608f  /* sqrt(1/(0.07*ln2)): A pre-scaled so e^{z} = 2^{dot'} */
#define LN2F 0.69314718056f

#define WS_T_OFF (N_ROWS * DIM * 2)
#define WS_D_OFF (WS_T_OFF + N_ROWS * 4)

#define GLOAD_LDS(g, l)                                        \
    __builtin_amdgcn_global_load_lds(                          \
        (const __attribute__((address_space(1))) void*)(g),    \
        (__attribute__((address_space(3))) void*)(l), 16, 0, 0)

// Kernel 1: L2-normalize rows, scale by SQK1, emit bf16 A' to ws. Zeros T[]
// and d_out. Dg[row] = s2' = sum(bf16(SQK1*a)^2) = the MFMA diagonal, so the
// diagonal's bf16 rounding error cancels: loss_i = ln2*(log2(T'_i) - s2'_i).
__global__ void __launch_bounds__(256) normalize_kernel(const float* __restrict__ in,
                                                        bf16* __restrict__ out,
                                                        float* __restrict__ Tg,
                                                        float* __restrict__ Dg,
                                                        float* __restrict__ loss_out) {
    if (blockIdx.x == 0 && threadIdx.x == 0) loss_out[0] = 0.0f;
    if (blockIdx.x < 64) Tg[blockIdx.x * 256 + threadIdx.x] = 0.0f;

    const int row  = blockIdx.x * 4 + (threadIdx.x >> 6);
    const int lane = threadIdx.x & 63;
    const float4* rp = (const float4*)(in + (size_t)row * DIM);
    float4 v = rp[lane];
    float ss = v.x * v.x + v.y * v.y + v.z * v.z + v.w * v.w;
#pragma unroll
    for (int m = 1; m < 64; m <<= 1) ss += __shfl_xor(ss, m, 64);
    float inv = SQK1 / fmaxf(sqrtf(ss), 1e-12f);
    bf16x4 o;
    o[0] = (bf16)(v.x * inv);
    o[1] = (bf16)(v.y * inv);
    o[2] = (bf16)(v.z * inv);
    o[3] = (bf16)(v.w * inv);
    *(bf16x4*)(out + (size_t)row * DIM + lane * 4) = o;

    float f0 = (float)o[0], f1 = (float)o[1], f2 = (float)o[2], f3 = (float)o[3];
    float s2 = f0 * f0 + f1 * f1 + f2 * f2 + f3 * f3;
#pragma unroll
    for (int m = 1; m < 64; m <<= 1) s2 += __shfl_xor(s2, m, 64);
    if (lane == 0) Dg[row] = s2;
}

// Tree-reduce 16 floats across the 32 `lo` lanes; every lane ends with the
// full sum for register index r = (lo>>1)&15. (Correctness-proven R4-R10.)
#define TREE16(R, out)                                                     \
    do {                                                                   \
        float w8[8], w4[4], w2[2], w1, g_;                                 \
        _Pragma("unroll") for (int i_ = 0; i_ < 8; ++i_) {                 \
            g_ = (lo & 16) ? R[i_] : R[i_ + 8];                            \
            w8[i_] = ((lo & 16) ? R[i_ + 8] : R[i_]) + __shfl_xor(g_, 16); \
        }                                                                  \
        _Pragma("unroll") for (int i_ = 0; i_ < 4; ++i_) {                 \
            g_ = (lo & 8) ? w8[i_] : w8[i_ + 4];                           \
            w4[i_] = ((lo & 8) ? w8[i_ + 4] : w8[i_]) + __shfl_xor(g_, 8); \
        }                                                                  \
        _Pragma("unroll") for (int i_ = 0; i_ < 2; ++i_) {                 \
            g_ = (lo & 4) ? w4[i_] : w4[i_ + 2];                           \
            w2[i_] = ((lo & 4) ? w4[i_ + 2] : w4[i_]) + __shfl_xor(g_, 4); \
        }                                                                  \
        g_ = (lo & 2) ? w2[0] : w2[1];                                     \
        w1 = ((lo & 2) ? w2[1] : w2[0]) + __shfl_xor(g_, 2);               \
        out = w1 + __shfl_xor(w1, 1);                                      \
    } while (0)

// Kernel 2: symmetric A'A'^T + softmax denominator.
// R13 (resubmit; R2 bench was an infrastructure failure, no signal):
// (a) FLAT BALANCED SCHEDULE — R12's 2112 blocks over 1024 resident slots
// ran 3 rounds (1024+1024+64); the 64-block round idled 97% of the chip for
// ~31 us (OccupancyPercent 33 == (50+50+3)/3). Now exactly 1024 blocks;
// block b owns the contiguous flat tile range [b*129/4, (b+1)*129/4) of the
// 33024 upper-triangle tile-bodies, C(it) = 2*it*(257-it). af[] reloads +
// row-sum flushes happen at the rare it-segment boundaries.
// (b) ATOMIC OFF THE SERIAL CHAIN — R12's per-tile col atomic sat inside
// the vmcnt window: queue [loads(cur)4, atomic(prev), loads(next)4] meant
// vmcnt(4) waited on a contended cross-XCD atomic every tile. Now the
// atomic is unconditional (adds 0.0 on diagonal tiles -> uniform queue) and
// the wait is vmcnt(5) (first tile 4, last tile 1): retires exactly
// loads(cur), leaves [atomic, loads(next)] in flight.
__global__ void __launch_bounds__(256, 4)
loss_kernel(const bf16* __restrict__ A, float* __restrict__ Tg) {
    __shared__ bf16 Bs0[32 * DIM];          // 16 KB
    __shared__ bf16 Bs1[32 * DIM];          // 16 KB

    const int tid = threadIdx.x;
    const int w  = tid >> 6;      // wave = row-group: rows w*32..+31 of the 128-row strip
    const int l  = tid & 63;
    const int lo = l & 31, hi = l >> 5;

    // flat tile range for this block (32 or 33 tiles)
    const int tbeg = (int)(((unsigned)blockIdx.x * 129u) >> 2);
    const int tend = (int)((((unsigned)blockIdx.x + 1u) * 129u) >> 2);
    const int nrem = tend - tbeg;

    // decode starting (it, jc): C(it) = 2*it*(257-it) <= tbeg < C(it+1)
    int it = 0;
    while (2 * (it + 1) * (257 - (it + 1)) <= tbeg) ++it;
    int jc = 4 * it + (tbeg - 2 * it * (257 - it));

    // persistent A fragments for the wave's 32 rows (A-op: m=lo, k=hi*8+j)
    bf16x8 af[16];
#define LOAD_AF                                                              \
    do {                                                                     \
        const bf16* ap_ = A + (size_t)(it * 128 + w * 32 + lo) * DIM + hi * 8; \
        _Pragma("unroll") for (int k_ = 0; k_ < 16; ++k_)                    \
            af[k_] = *(const volatile bf16x8*)(ap_ + k_ * 16);               \
    } while (0)
    LOAD_AF;

    float s0[16];
#pragma unroll
    for (int r = 0; r < 16; ++r) s0[r] = 0.f;

    // DMA lane constants. Wave w stages B-tile rows w*8..+7 in 4 instrs
    // (2 rows each). Lane: rl = l>>5 (row in pair), s = l&31 (LDS slot).
    // Slot s of row r holds global chunk c = (s&24)|((s&7)^(r&7)).
    const int s_dma = l & 31;
    const int rl    = l >> 5;
    int vo[4];
#pragma unroll
    for (int q = 0; q < 4; ++q) {
        const int c = (s_dma & 24) | ((s_dma & 7) ^ ((q * 2 + rl) & 7));
        vo[q] = rl * DIM + c * 8;
    }

    // fragment-read constants: B row = lo; chunk cc at slot (cc&24)|((cc&7)^(lo&7))
    const int rbase = lo * DIM;
    const int mx7 = lo & 7;

#define ISSUE(jcn_, BUF)                                                     \
    do {                                                                     \
        const bf16* tb_ = A + (size_t)((jcn_) * 32 + w * 8) * DIM;           \
        bf16* lb_ = &BUF[(w * 8) * DIM];                                     \
        _Pragma("unroll") for (int q_ = 0; q_ < 4; ++q_) {                   \
            GLOAD_LDS(tb_ + (q_ * 2) * DIM + vo[q_],                         \
                      lb_ + (q_ * 2) * DIM);                                 \
        }                                                                    \
    } while (0)

#define FLUSH_ROWS                                                           \
    do {                                                                     \
        float tr_;                                                           \
        TREE16(s0, tr_);                                                     \
        const int r_ = (lo >> 1) & 15;                                       \
        const int rowoff_ = (r_ & 3) + 8 * (r_ >> 2) + 4 * hi;               \
        if ((l & 1) == 0)                                                    \
            atomicAdd(&Tg[it * 128 + w * 32 + rowoff_], tr_);                \
    } while (0)

    int t = 0, jcn, itn;
    bool has_next;

#define NEXT_DECODE                                                          \
    do {                                                                     \
        has_next = (t + 1 < nrem);                                           \
        if (has_next) {                                                      \
            jcn = jc + 1; itn = it;                                          \
            if (jcn == NJC) { itn = it + 1; jcn = 4 * itn; }                 \
        } else { jcn = jc; itn = it; }                                       \
    } while (0)

    // WN = steady wait (next issued), WL = last-tile wait (no next issued)
#define TILE_BODY(BR, BW, WN, WL)                                            \
    do {                                                                     \
        asm volatile("s_barrier" ::: "memory");                              \
        if (has_next) {                                                      \
            ISSUE(jcn, BW);                                                  \
            asm volatile("s_waitcnt vmcnt(" #WN ")" ::: "memory");           \
        } else {                                                             \
            asm volatile("s_waitcnt vmcnt(" #WL ")" ::: "memory");           \
        }                                                                    \
        asm volatile("s_barrier" ::: "memory");                              \
        f32x16 c0;                                                           \
        _Pragma("unroll") for (int r_ = 0; r_ < 16; ++r_) c0[r_] = 0.f;      \
        __builtin_amdgcn_s_setprio(1);                                       \
        _Pragma("unroll") for (int k_ = 0; k_ < 16; ++k_) {                  \
            const int cc_ = k_ * 2 + hi;                                     \
            const int slot_ = (cc_ & 24) | ((cc_ & 7) ^ mx7);                \
            bf16x8 b_ = *(const bf16x8*)&BR[rbase + slot_ * 8];              \
            c0 = __builtin_amdgcn_mfma_f32_32x32x16_bf16(af[k_], b_, c0, 0, 0, 0); \
        }                                                                    \
        __builtin_amdgcn_s_setprio(0);                                       \
        float cs_ = 0.f;                                                     \
        _Pragma("unroll") for (int r_ = 0; r_ < 16; ++r_) {                  \
            float e_ = __builtin_amdgcn_exp2f(c0[r_]);                       \
            s0[r_] += e_;                                                    \
            cs_ += e_;                                                       \
        }                                                                    \
        cs_ += __shfl_xor(cs_, 32);                                          \
        /* col-sum flush: UNCONDITIONAL instr (uniform vmcnt queue); adds  */ \
        /* 0.0 on the diagonal 128x128 block (covered by row sums).        */ \
        const float fv_ = ((jc >> 2) == it) ? 0.0f : cs_;                    \
        if (hi == 0) atomicAdd(&Tg[jc * 32 + lo], fv_);                      \
    } while (0)

    // advance to next tile; at it-segment boundary: flush row sums, reload af
#define ADVANCE                                                              \
    do {                                                                     \
        ++t;                                                                 \
        if (itn != it) {                                                     \
            FLUSH_ROWS;                                                      \
            it = itn;                                                        \
            LOAD_AF;                                                         \
            _Pragma("unroll") for (int r_ = 0; r_ < 16; ++r_) s0[r_] = 0.f;  \
        }                                                                    \
        jc = jcn;                                                            \
    } while (0)

    ISSUE(jc, Bs0);
    // peeled first tile: no atomic in the queue yet -> vmcnt(4)/(0)
    NEXT_DECODE;
    TILE_BODY(Bs0, Bs1, 4, 0);
    ADVANCE;
    while (t < nrem) {
        NEXT_DECODE;
        TILE_BODY(Bs1, Bs0, 5, 1);
        ADVANCE;
        if (t >= nrem) break;
        NEXT_DECODE;
        TILE_BODY(Bs0, Bs1, 5, 1);
        ADVANCE;
    }
    FLUSH_ROWS;

#undef ISSUE
#undef TILE_BODY
#undef NEXT_DECODE
#undef ADVANCE
#undef FLUSH_ROWS
#undef LOAD_AF
}

// Kernel 3: loss_i = ln2*(log2(T'_i) - s2'_i), mean over rows.
__global__ void __launch_bounds__(256) final_kernel(const float* __restrict__ Tg,
                                                    const float* __restrict__ Dg,
                                                    float* __restrict__ out) {
    __shared__ float red[4];
    const int i = blockIdx.x * 256 + threadIdx.x;
    float c = LN2F * (__log2f(Tg[i]) - Dg[i]) * (1.0f / (float)N_ROWS);
#pragma unroll
    for (int m = 1; m < 64; m <<= 1) c += __shfl_xor(c, m, 64);
    if ((threadIdx.x & 63) == 0) red[threadIdx.x >> 6] = c;
    __syncthreads();
    if (threadIdx.x == 0)
        atomicAdd(out, red[0] + red[1] + red[2] + red[3]);
}

extern "C" void kernel_launch(void* const* d_in, const int* in_sizes, int n_in,
                              void* d_out, int out_size, void* d_ws, size_t ws_size,
                              hipStream_t stream) {
    const float* emb = (const float*)d_in[0];
    float* out = (float*)d_out;
    bf16* Abf = (bf16*)d_ws;
    float* Tg = (float*)((char*)d_ws + WS_T_OFF);
    float* Dg = (float*)((char*)d_ws + WS_D_OFF);

    hipLaunchKernelGGL(normalize_kernel, dim3(N_ROWS / 4), dim3(256), 0, stream,
                       emb, Abf, Tg, Dg, out);
    hipLaunchKernelGGL(loss_kernel, dim3(NBLKS), dim3(256), 0, stream,
                       Abf, Tg);
    hipLaunchKernelGGL(final_kernel, dim3(N_ROWS / 256), dim3(256), 0, stream,
                       Tg, Dg, out);
}